// Round 1
// baseline (327.198 us; speedup 1.0000x reference)
//
#include <hip/hip_runtime.h>

// RegionProposal: decode 55296 anchors, top-6000 by score (stable), greedy NMS
// (IoU>0.7), output first 300 kept boxes zero-padded to [300,4] fp32.
//
// Pipeline (all on `stream`):
//   memset(hist+cnt) -> k_decode (keys/roi/hist) -> k_cutoff (find 16-bit bin
//   cutoff for rank 6000) -> k_compact (candidates <= cutoff bin) ->
//   k_sort (single-block bitonic of 8192 u64 keys in LDS, gather boxes) ->
//   k_nms (single wave, check-against-kept-list greedy NMS, early exit at 300
//   kept, writes d_out directly).
//
// Sort key = (flip(logit) << 32) | anchor_idx : descending logit, ascending
// index tie-break == stable argsort(-sigmoid(logit)) since sigmoid is strictly
// monotone. No sigmoid computed at all.

#define HDIM 64
#define WDIM 96
#define ADIM 9
#define NANCH 55296          // HDIM*WDIM*ADIM
#define HWSZ 6144            // HDIM*WDIM
#define TOPK 6000
#define OUTK 300
#define CAND_CAP 8192

// ws layout (bytes):
//   0       : hist  u32[65536]          (262144)  -- zeroed each call
//   262144  : cnt   u32                 (4)       -- zeroed each call
//   262148  : meta  u32 (cutoff bin B)  (4)
//   262400  : keys  u64[NANCH]          (442368)
//   704768  : roi   float4[NANCH]       (884736)
//   1589504 : cand  u64[CAND_CAP]       (65536)
//   1655040 : sboxes float4[TOPK]       (96000)
//   total 1751040 bytes

__device__ __forceinline__ unsigned flip32(float f) {
    unsigned b = __float_as_uint(f);
    unsigned u = (b & 0x80000000u) ? ~b : (b | 0x80000000u); // ascending u == ascending f
    return ~u;                                               // ascending fs == DESCENDING f
}

__global__ void k_decode(const float* __restrict__ cls,
                         const float* __restrict__ loc,
                         const float* __restrict__ anc,
                         unsigned long long* __restrict__ keys,
                         float4* __restrict__ roi,
                         unsigned* __restrict__ hist) {
    int n = blockIdx.x * 256 + threadIdx.x;
    if (n >= NANCH) return;
    int a  = n % ADIM;
    int hw = n / ADIM;

    // class-1 logit: NCHW channel 2a+1
    float logit = cls[(2 * a + 1) * HWSZ + hw];
    unsigned fs = flip32(logit);
    keys[n] = ((unsigned long long)fs << 32) | (unsigned)n;
    atomicAdd(&hist[fs >> 16], 1u);

    float t0 = loc[(4 * a + 0) * HWSZ + hw];
    float t1 = loc[(4 * a + 1) * HWSZ + hw];
    float t2 = loc[(4 * a + 2) * HWSZ + hw];
    float t3 = loc[(4 * a + 3) * HWSZ + hw];
    float4 an = reinterpret_cast<const float4*>(anc)[n];   // (cx, cy, w, h)

    float cx = t0 * an.z + an.x;
    float cy = t1 * an.w + an.y;
    float bw = expf(t2) * an.z;
    float bh = expf(t3) * an.w;
    float x1 = fminf(fmaxf(cx - bw * 0.5f, 0.f), 1.f);
    float y1 = fminf(fmaxf(cy - bh * 0.5f, 0.f), 1.f);
    float x2 = fminf(fmaxf(cx + bw * 0.5f, 0.f), 1.f);
    float y2 = fminf(fmaxf(cy + bh * 0.5f, 0.f), 1.f);
    roi[n] = make_float4(x1, y1, x2, y2);
}

// Find smallest 16-bit bin B with cumulative count >= TOPK.
__global__ void k_cutoff(const unsigned* __restrict__ hist,
                         unsigned* __restrict__ meta) {
    __shared__ unsigned partial[256];
    int t = threadIdx.x;
    unsigned s = 0;
    const uint4* h4 = reinterpret_cast<const uint4*>(hist + t * 256);
    #pragma unroll 4
    for (int i = 0; i < 64; ++i) { uint4 v = h4[i]; s += v.x + v.y + v.z + v.w; }
    partial[t] = s;
    __syncthreads();
    if (t == 0) {
        unsigned cum = 0; int c = 0;
        while (c < 256 && cum + partial[c] < TOPK) { cum += partial[c]; ++c; }
        unsigned B = 65535u;
        for (int k = c * 256; k < c * 256 + 256; ++k) {
            unsigned hv = hist[k];
            if (cum + hv >= TOPK) { B = (unsigned)k; break; }
            cum += hv;
        }
        meta[0] = B;
    }
}

__global__ void k_compact(const unsigned long long* __restrict__ keys,
                          const unsigned* __restrict__ meta,
                          unsigned long long* __restrict__ cand,
                          unsigned* __restrict__ cnt) {
    int n = blockIdx.x * 256 + threadIdx.x;
    if (n >= NANCH) return;
    unsigned long long key = keys[n];
    unsigned bin = (unsigned)(key >> 48);
    if (bin <= meta[0]) {
        unsigned pos = atomicAdd(cnt, 1u);
        if (pos < CAND_CAP) cand[pos] = key;  // order random; full sort follows
    }
}

// Single-block bitonic sort of CAND_CAP u64 keys in LDS, then gather top-6000 boxes.
__global__ void __launch_bounds__(512) k_sort(const unsigned long long* __restrict__ cand,
                                              const unsigned* __restrict__ cnt,
                                              const float4* __restrict__ roi,
                                              float4* __restrict__ sboxes) {
    __shared__ unsigned long long s[CAND_CAP];   // 64 KiB
    int t = threadIdx.x;
    unsigned C = *cnt; if (C > CAND_CAP) C = CAND_CAP;
    for (int i = t; i < CAND_CAP; i += 512) s[i] = (i < (int)C) ? cand[i] : ~0ull;
    __syncthreads();
    for (unsigned k = 2; k <= CAND_CAP; k <<= 1) {
        for (unsigned j = k >> 1; j >= 1; j >>= 1) {
            for (unsigned p = (unsigned)t; p < CAND_CAP / 2; p += 512) {
                unsigned i = ((p & ~(j - 1)) << 1) | (p & (j - 1)); // (i & j) == 0
                unsigned l = i | j;
                bool up = ((i & k) == 0);
                unsigned long long x = s[i], y = s[l];
                if ((x > y) == up) { s[i] = y; s[l] = x; }
            }
            __syncthreads();
        }
    }
    for (int r = t; r < TOPK; r += 512) {
        unsigned idx = (unsigned)(s[r] & 0xFFFFFFFFull);
        sboxes[r] = roi[idx];
    }
}

// Greedy NMS, single wave. Box i kept iff IoU <= 0.7 with every earlier kept
// box. Early exit once 300 kept (later boxes cannot affect the first 300 kept).
__global__ void k_nms(const float4* __restrict__ sboxes, float4* __restrict__ out) {
    __shared__ float4 kept[OUTK];
    __shared__ float  karea[OUTK];
    int lane = threadIdx.x;   // blockDim == 64, one wave
    int kc = 0;
    for (int i = 0; i < TOPK && kc < OUTK; ++i) {
        float4 b = sboxes[i];
        float ab = (b.z - b.x) * (b.w - b.y);
        bool sup = false;
        for (int j = lane; j < kc; j += 64) {
            float4 kb = kept[j];
            float ix = fminf(b.z, kb.z) - fmaxf(b.x, kb.x);
            float iy = fminf(b.w, kb.w) - fmaxf(b.y, kb.y);
            float inter = fmaxf(ix, 0.f) * fmaxf(iy, 0.f);
            float uni = ab + karea[j] - inter;
            if (inter / fmaxf(uni, 1e-12f) > 0.7f) sup = true;
        }
        if (!__any(sup ? 1 : 0)) {
            if (lane == 0) { kept[kc] = b; karea[kc] = ab; }
            kc++;
        }
        __syncthreads();   // one wave: cheap; orders LDS append vs next reads
    }
    for (int r = lane; r < OUTK; r += 64) {
        float4 z = make_float4(0.f, 0.f, 0.f, 0.f);
        out[r] = (r < kc) ? kept[r] : z;
    }
}

extern "C" void kernel_launch(void* const* d_in, const int* in_sizes, int n_in,
                              void* d_out, int out_size, void* d_ws, size_t ws_size,
                              hipStream_t stream) {
    const float* cls = (const float*)d_in[0];   // (1, 18, 64, 96)
    const float* loc = (const float*)d_in[1];   // (1, 36, 64, 96)
    const float* anc = (const float*)d_in[2];   // (55296, 4)

    char* ws = (char*)d_ws;                     // needs 1,751,040 bytes
    unsigned*            hist   = (unsigned*)(ws + 0);
    unsigned*            cnt    = (unsigned*)(ws + 262144);
    unsigned*            meta   = (unsigned*)(ws + 262148);
    unsigned long long*  keys   = (unsigned long long*)(ws + 262400);
    float4*              roi    = (float4*)(ws + 704768);
    unsigned long long*  cand   = (unsigned long long*)(ws + 1589504);
    float4*              sboxes = (float4*)(ws + 1655040);

    // hist + cnt must be zero every call (ws is not re-poisoned between replays)
    hipMemsetAsync(ws, 0, 262152, stream);

    k_decode <<<NANCH / 256, 256, 0, stream>>>(cls, loc, anc, keys, roi, hist);
    k_cutoff <<<1, 256, 0, stream>>>(hist, meta);
    k_compact<<<NANCH / 256, 256, 0, stream>>>(keys, meta, cand, cnt);
    k_sort   <<<1, 512, 0, stream>>>(cand, cnt, roi, sboxes);
    k_nms    <<<1, 64, 0, stream>>>(sboxes, (float4*)d_out);
}

// Round 2
// 66.775 us; speedup vs baseline: 4.9000x; 4.9000x over previous
//
#include <hip/hip_runtime.h>

// RegionProposal: decode 55296 anchors, stable top-6000 by score, greedy NMS
// (IoU > 0.7), output first 300 kept boxes zero-padded to [300,4] fp32.
//
// Two kernels:
//   k_decode (216 blocks): fs[n] = flip32(class-1 logit)  (sort key hi bits;
//            idx implicit), roi[n] = decoded+clipped box.
//   k_mega   (1 block x 1024): LDS histogram -> rank-1024/rank-6000 cutoffs ->
//            LDS compact (S region = top ~1300, L region = rest of top ~6300)
//            -> bitonic sort S (2048 slots) -> chunked 16-wave NMS with early
//            exit at 300 kept. Fallback (pathological data): full 8192 sort,
//            continue NMS. All counters/state in LDS -> no memset, no global
//            atomics, deterministic (sort fixes atomic append order; keys
//            unique via idx).
//
// Key = (flip32(logit) << 32) | n : ascending u64 == descending logit, ties by
// ascending index == reference's stable argsort(-sigmoid(logit)). Identical
// numerics (fp32 decode, division-form IoU) to the round-1 kernel that passed
// with absmax 0.0.

#define HDIM 64
#define WDIM 96
#define ADIM 9
#define NANCH 55296
#define HWSZ 6144
#define TOPK 6000
#define OUTK 300
#define NBINS 16384   // top 14 bits of flipped score
#define CAP 8192
#define SCAP 2048
#define LCAP 6144     // CAP - SCAP
#define RANK1 1024
#define THR 0.7f

typedef unsigned long long u64;
typedef unsigned int u32;

__device__ __forceinline__ u32 flip32(float f) {
    u32 b = __float_as_uint(f);
    u32 u = (b & 0x80000000u) ? ~b : (b | 0x80000000u); // ascending u == ascending f
    return ~u;                                          // ascending fs == DESCENDING f
}

__device__ __forceinline__ bool iou_gt(float4 a, float aa, float4 b, float ba) {
    float ix = fminf(a.z, b.z) - fmaxf(a.x, b.x);
    float iy = fminf(a.w, b.w) - fmaxf(a.y, b.y);
    float inter = fmaxf(ix, 0.f) * fmaxf(iy, 0.f);
    float uni = aa + ba - inter;
    return inter / fmaxf(uni, 1e-12f) > THR;   // division form == reference
}

__global__ void k_decode(const float* __restrict__ cls,
                         const float* __restrict__ loc,
                         const float* __restrict__ anc,
                         u32* __restrict__ fsarr,
                         float4* __restrict__ roi) {
    int n = blockIdx.x * 256 + threadIdx.x;
    if (n >= NANCH) return;
    int a = n % ADIM, hw = n / ADIM;
    float logit = cls[(2 * a + 1) * HWSZ + hw];
    fsarr[n] = flip32(logit);

    float t0 = loc[(4 * a + 0) * HWSZ + hw];
    float t1 = loc[(4 * a + 1) * HWSZ + hw];
    float t2 = loc[(4 * a + 2) * HWSZ + hw];
    float t3 = loc[(4 * a + 3) * HWSZ + hw];
    float4 an = reinterpret_cast<const float4*>(anc)[n];
    float cx = t0 * an.z + an.x;
    float cy = t1 * an.w + an.y;
    float bw = expf(t2) * an.z;
    float bh = expf(t3) * an.w;
    float x1 = fminf(fmaxf(cx - bw * 0.5f, 0.f), 1.f);
    float y1 = fminf(fmaxf(cy - bh * 0.5f, 0.f), 1.f);
    float x2 = fminf(fmaxf(cx + bw * 0.5f, 0.f), 1.f);
    float y2 = fminf(fmaxf(cy + bh * 0.5f, 0.f), 1.f);
    roi[n] = make_float4(x1, y1, x2, y2);
}

// Chunked greedy NMS over sorted cand[i0, limit). 16 waves: wave w checks the
// 64-candidate chunk against kept[w::16]; wave 0 builds the in-chunk 64x64
// pairwise suppression and resolves greedy order via iterated ballot
// (fixed point of X_{k+1} = {l alive : no suppressor of l in X_k} = greedy set).
// shu[4] = kc (kept count, persists across calls), shu[5] = next rank.
__device__ __forceinline__ void nms_run(u32 limit, u64* cand,
                                        const float4* __restrict__ roi,
                                        float4* kept, float* karea,
                                        float4* cbox, float* carea,
                                        u64* supw, u64* sbyp, u32* shu,
                                        float4* out, int wid, int lane) {
    while (true) {
        __syncthreads();                       // orders prev chunk's LDS writes
        u32 kc = shu[4], i0 = shu[5];
        if (kc >= OUTK || i0 >= limit) break;  // uniform

        if (wid == 0) {                        // gather chunk boxes
            bool valid = (i0 + (u32)lane) < limit;
            u64 key = cand[i0 + lane];
            u32 idx = valid ? (u32)key : 0u;
            float4 b = roi[idx];
            cbox[lane] = b;
            carea[lane] = (b.z - b.x) * (b.w - b.y);
        }
        __syncthreads();

        float4 c = cbox[lane];
        float ca = carea[lane];

        // vs-kept, strided across the 16 waves
        bool sup = false;
        for (u32 j = (u32)wid; j < kc; j += 16)
            sup = sup || iou_gt(c, ca, kept[j], karea[j]);
        u64 bal = __ballot(sup ? 1 : 0);
        if (lane == 0) supw[wid] = bal;

        // in-chunk pairwise (rotations split across waves: wave w -> s=4w+1..4w+4)
        u64 sby = 0;
        u32 smax = 4u * wid + 4u; if (smax > 63u) smax = 63u;
        for (u32 s = 4u * wid + 1u; s <= smax; ++s) {
            u32 p = ((u32)lane + s) & 63u;
            if (p < (u32)lane && (i0 + p) < limit) {
                if (iou_gt(c, ca, cbox[p], carea[p])) sby |= (1ull << p);
            }
        }
        sbyp[wid * 64 + lane] = sby;
        __syncthreads();

        if (wid == 0) {
            u64 sup64 = 0, sbyfull = 0;
            #pragma unroll
            for (int w = 0; w < 16; ++w) {
                sup64 |= supw[w];
                sbyfull |= sbyp[w * 64 + lane];
            }
            bool valid = (i0 + (u32)lane) < limit;
            bool ia = valid && !((sup64 >> lane) & 1);
            u64 A = __ballot(ia ? 1 : 0);
            for (int it = 0; it < 64; ++it) {          // converges in ~2-5 steps
                bool na = ia && ((sbyfull & A) == 0);
                u64 A2 = __ballot(na ? 1 : 0);
                if (A2 == A) break;
                A = A2;
            }
            bool kp = (A >> lane) & 1;
            u32 rank = (u32)__popcll(A & ((1ull << lane) - 1ull));
            if (kp && kc + rank < OUTK) {
                kept[kc + rank] = c;
                karea[kc + rank] = ca;
                out[kc + rank] = c;                    // emit directly
            }
            if (lane == 0) {
                u32 nkc = kc + (u32)__popcll(A);
                shu[4] = (nkc > OUTK) ? OUTK : nkc;
                shu[5] = i0 + 64;
            }
        }
    }
}

__global__ void __launch_bounds__(1024) k_mega(const u32* __restrict__ fsarr,
                                               const float4* __restrict__ roi,
                                               float4* __restrict__ out) {
    __shared__ u64 cand[CAP];        // 64 KB; aliased as u32 hist[16384] in A/B
    __shared__ float4 kept[OUTK];    // 4800 B; aliased as u32 part[1024] in B
    __shared__ float karea[OUTK];
    __shared__ float4 cbox[64];
    __shared__ float carea[64];
    __shared__ u64 supw[16];
    __shared__ u64 sbyp[16 * 64];    // 8 KB
    __shared__ u32 shu[16];          // 0:cntS 1:cntL 2:B1 3:B2 4:kc 5:i0

    const int tid = threadIdx.x;
    const int wid = tid >> 6;
    const int lane = tid & 63;
    u32* hist = (u32*)cand;
    u32* part = (u32*)kept;

    // ---- Phase A: 16384-bin LDS histogram of fs top-14 bits ----
    for (int i = tid; i < NBINS; i += 1024) hist[i] = 0;
    if (tid < 16) shu[tid] = 0;
    __syncthreads();
    const uint4* f4 = reinterpret_cast<const uint4*>(fsarr);
    for (int i = tid; i < NANCH / 4; i += 1024) {
        uint4 v = f4[i];
        atomicAdd(&hist[v.x >> 18], 1u);
        atomicAdd(&hist[v.y >> 18], 1u);
        atomicAdd(&hist[v.z >> 18], 1u);
        atomicAdd(&hist[v.w >> 18], 1u);
    }
    __syncthreads();

    // ---- Phase B: prefix scan of 16-bin chunks; find rank-1024 / rank-6000 bins
    {
        int base = tid * 16;
        u32 s = 0;
        #pragma unroll
        for (int b = 0; b < 16; ++b) s += hist[base + b];
        part[tid] = s;
    }
    __syncthreads();
    for (int off = 1; off < 1024; off <<= 1) {
        u32 v = (tid >= off) ? part[tid - off] : 0u;
        __syncthreads();
        part[tid] += v;
        __syncthreads();
    }
    {
        u32 before = tid ? part[tid - 1] : 0u;
        u32 endv = part[tid];
        if (before < RANK1 && endv >= RANK1) {
            u32 run = before;
            for (int b = 0; b < 16; ++b) {
                run += hist[tid * 16 + b];
                if (run >= RANK1) { shu[2] = (u32)(tid * 16 + b); break; }
            }
        }
        if (before < TOPK && endv >= TOPK) {
            u32 run = before;
            for (int b = 0; b < 16; ++b) {
                run += hist[tid * 16 + b];
                if (run >= TOPK) { shu[3] = (u32)(tid * 16 + b); break; }
            }
        }
    }
    __syncthreads();
    u32 B1 = shu[2], B2 = shu[3];

    // ---- Phase C: compact candidates into LDS (S front, L back) ----
    for (int i = tid; i < CAP; i += 1024) cand[i] = ~0ull;   // hist dead now
    __syncthreads();
    for (int i = tid; i < NANCH / 4; i += 1024) {
        uint4 v = f4[i];
        #pragma unroll
        for (int c = 0; c < 4; ++c) {
            u32 fs = (c == 0) ? v.x : (c == 1) ? v.y : (c == 2) ? v.z : v.w;
            u32 bin = fs >> 18;
            if (bin <= B2) {
                u64 key = ((u64)fs << 32) | (u32)(i * 4 + c);
                if (bin <= B1) {
                    u32 p = atomicAdd(&shu[0], 1u);
                    if (p < SCAP) { cand[p] = key; continue; }
                }
                u32 q = atomicAdd(&shu[1], 1u);
                if (q < LCAP) cand[CAP - 1 - q] = key;
            }
        }
    }
    __syncthreads();
    u32 cs = shu[0], cl = shu[1];
    u32 inS = cs < SCAP ? cs : SCAP;
    u32 inL = cl < LCAP ? cl : LCAP;
    u32 total = inS + inL;
    bool fast = (cs <= SCAP);

    // ---- Phase D/E fast path: sort S region (2048), NMS over it ----
    if (fast) {
        for (u32 k = 2; k <= SCAP; k <<= 1) {
            for (u32 j = k >> 1; j >= 1; j >>= 1) {
                u32 p = (u32)tid;                         // 1024 CEs = SCAP/2
                u32 i = ((p & ~(j - 1)) << 1) | (p & (j - 1));
                u32 l2 = i | j;
                bool up = ((i & k) == 0);
                u64 x = cand[i], y = cand[l2];
                if ((x > y) == up) { cand[i] = y; cand[l2] = x; }
                __syncthreads();
            }
        }
        if (tid == 0) shu[5] = 0;
        nms_run(cs, cand, roi, kept, karea, cbox, carea, supw, sbyp, shu, out, wid, lane);
    }

    // ---- Fallback: full 8192 sort + continue (rare; also handles cs > SCAP) ----
    u32 kcF = shu[4];                 // stable: last writes fenced by nms_run's barrier
    u32 i0fb = fast ? cs : 0u;
    u32 limfb = total < TOPK ? total : TOPK;
    if (kcF < OUTK && i0fb < limfb) {
        __syncthreads();
        for (u32 k = 2; k <= CAP; k <<= 1) {
            for (u32 j = k >> 1; j >= 1; j >>= 1) {
                for (u32 p = (u32)tid; p < CAP / 2; p += 1024) {
                    u32 i = ((p & ~(j - 1)) << 1) | (p & (j - 1));
                    u32 l2 = i | j;
                    bool up = ((i & k) == 0);
                    u64 x = cand[i], y = cand[l2];
                    if ((x > y) == up) { cand[i] = y; cand[l2] = x; }
                }
                __syncthreads();
            }
        }
        if (tid == 0) shu[5] = i0fb;
        nms_run(limfb, cand, roi, kept, karea, cbox, carea, supw, sbyp, shu, out, wid, lane);
    }

    // ---- Zero-pad output ----
    __syncthreads();
    u32 kc = shu[4];
    for (u32 r = (u32)tid; r < OUTK; r += 1024)
        if (r >= kc) out[r] = make_float4(0.f, 0.f, 0.f, 0.f);
}

extern "C" void kernel_launch(void* const* d_in, const int* in_sizes, int n_in,
                              void* d_out, int out_size, void* d_ws, size_t ws_size,
                              hipStream_t stream) {
    const float* cls = (const float*)d_in[0];   // (1, 18, 64, 96)
    const float* loc = (const float*)d_in[1];   // (1, 36, 64, 96)
    const float* anc = (const float*)d_in[2];   // (55296, 4)

    char* ws = (char*)d_ws;                     // needs 1,105,920 bytes
    u32*    fsarr = (u32*)(ws + 0);             // 221184 B
    float4* roi   = (float4*)(ws + 221184);     // 884736 B

    k_decode<<<NANCH / 256, 256, 0, stream>>>(cls, loc, anc, fsarr, roi);
    k_mega  <<<1, 1024, 0, stream>>>(fsarr, roi, (float4*)d_out);
}